// Round 6
// baseline (370.988 us; speedup 1.0000x reference)
//
#include <hip/hip_runtime.h>
#include <math.h>

#define DD 160
#define HH 160
#define WW 160
#define NB 2
#define SLICE (HH * WW)        // 25600
#define NV 51200               // NB*160*160 vectors per reduction type
#define NVTOT (4 * NV)         // gxH, gzH, gyD, gzD
#define NC 10                  // chunks per reduced axis
#define RPC 16                 // rows (slices) per chunk
#define NTHR 320               // 8 groups x 40 float4-lanes

static constexpr float EPS = 1e-12f;
static constexpr float SCALE = -1.0f / 960.0f;  // -(six cos sums)/(160*2*3)

#define ELEM(v, j) ((j) == 0 ? (v).x : ((j) == 1 ? (v).y : ((j) == 2 ? (v).z : (v).w)))

__global__ void zero_kernel(float* out) {
  if (threadIdx.x == 0) out[0] = 0.0f;
}

// ---------------------------------------------------------------------------
// Fused main pass (R4 structure, no shuffles). Even blocks: role A (h-walk):
// alongW cosines (gx,gy) deferred via LDS + alongH partials (gx,gz). Odd
// blocks: role B (d-walk): alongD partials (gy,gz). Group g owns 2 CONSECUTIVE
// rows (register reuse of the h+1 self-load). Column partials accumulate via
// LDS atomicAdd into a small sd2 (4 KB) instead of a 32 KB dump array.
// ---------------------------------------------------------------------------
__global__ __launch_bounds__(NTHR) void mainAB(const float* __restrict__ f,
                                               const float* __restrict__ t,
                                               float* __restrict__ P,
                                               float* __restrict__ out) {
  __shared__ float sd[RPC * 40 * 7];    // 4480 f: per-(row,lane) alongW partials (A)
  __shared__ float sd2[40 * 25];        // 1000 f: column partials [l][j*6+c]
  __shared__ float red[RPC][6];
  __shared__ float cpad[RPC];
  const int tid = threadIdx.x;
  const int g = tid / 40;               // group 0..7
  const int l = tid % 40;               // float4-lane within row
  const int w = 4 * l;
  const int wn = (w + 4 < WW) ? (w + 4) : (WW - 1);  // clamp -> gz[3]=0 at w=159
  const int blk = blockIdx.x;
  const bool roleA = ((blk & 1) == 0);
  const int id = blk >> 1;

  for (int i = tid; i < 1000; i += NTHR) sd2[i] = 0.0f;

  float acc[24];                        // alongH (A) or alongD (B) partials
#pragma unroll
  for (int c = 0; c < 24; ++c) acc[c] = 0.0f;

  int vbase1, vbase2, ch;

  if (roleA) {
    // ---------------- role A (h-walk) ----------------
    const int hc = id % NC;
    const int bd = id / NC;
    const int d = bd % DD;
    const size_t base = (size_t)bd * SLICE;
    const float* fp = f + base;
    const float* tp = t + base;
    const int dstep = (d < DD - 1) ? SLICE : 0;     // clamp -> gx = 0
    vbase1 = bd * 160;                  // gx alongH
    vbase2 = NV + bd * 160;             // gz alongH
    ch = hc;
    const int h0 = hc * RPC + g * 2;
    float4 F0 = *(const float4*)(fp + h0 * WW + w);
    float4 T0 = *(const float4*)(tp + h0 * WW + w);

#pragma unroll
    for (int it = 0; it < 2; ++it) {
      const int h = h0 + it;
      const int hstep = (h < HH - 1) ? WW : 0;      // clamp -> gy = 0
      const float* rf = fp + h * WW;
      const float* rt = tp + h * WW;
      const float4 FD = *(const float4*)(rf + dstep + w);
      const float4 TD = *(const float4*)(rt + dstep + w);
      const float4 F1 = *(const float4*)(rf + hstep + w);   // row h+1 self
      const float4 T1 = *(const float4*)(rt + hstep + w);
      const float fz = rf[wn], tz = rt[wn];
      float xd = 0, xf = 0, xt = 0, yd = 0, yf = 0, yt = 0;
#pragma unroll
      for (int j = 0; j < 4; ++j) {
        const float f0 = ELEM(F0, j), t0 = ELEM(T0, j);
        const float gxf = ELEM(FD, j) - f0, gxt = ELEM(TD, j) - t0;
        const float gyf = ELEM(F1, j) - f0, gyt = ELEM(T1, j) - t0;
        const float fnx = (j < 3) ? ELEM(F0, j + 1) : fz;
        const float tnx = (j < 3) ? ELEM(T0, j + 1) : tz;
        const float gzf = fnx - f0, gzt = tnx - t0;
        xd += gxf * gxt; xf += gxf * gxf; xt += gxt * gxt;
        yd += gyf * gyt; yf += gyf * gyf; yt += gyt * gyt;
        acc[j * 6 + 0] += gxf * gxt; acc[j * 6 + 1] += gxf * gxf; acc[j * 6 + 2] += gxt * gxt;
        acc[j * 6 + 3] += gzf * gzt; acc[j * 6 + 4] += gzf * gzf; acc[j * 6 + 5] += gzt * gzt;
      }
      F0 = F1; T0 = T1;                 // register reuse: next row's self
      float* s = &sd[((g * 2 + it) * 40 + l) * 7];  // each slot written once
      s[0] = xd; s[1] = xf; s[2] = xt; s[3] = yd; s[4] = yf; s[5] = yt;
    }
    __syncthreads();
    // alongW reduce over 40 lanes: 96 tasks (16 rows x 6 sums)
    if (tid < RPC * 6) {
      const int row = tid / 6, c = tid % 6;
      float s = 0.0f;
#pragma unroll 8
      for (int ll = 0; ll < 40; ++ll) s += sd[(row * 40 + ll) * 7 + c];
      red[row][c] = s;
    }
    __syncthreads();
    if (tid < RPC) {
      const float cx = red[tid][0] / (fmaxf(sqrtf(red[tid][1]), EPS) * fmaxf(sqrtf(red[tid][2]), EPS));
      const float cy = red[tid][3] / (fmaxf(sqrtf(red[tid][4]), EPS) * fmaxf(sqrtf(red[tid][5]), EPS));
      cpad[tid] = cx + cy;
    }
  } else {
    // ---------------- role B (d-walk) ----------------
    const int dc = id % NC;
    const int bh = id / NC;
    const int b = bh / HH;
    const int h = bh % HH;
    const float* fp = f + (size_t)b * DD * SLICE + (size_t)h * WW;
    const float* tp = t + (size_t)b * DD * SLICE + (size_t)h * WW;
    const int hstep = (h < HH - 1) ? WW : 0;        // clamp -> gy = 0
    vbase1 = 2 * NV + bh * 160;         // gy alongD
    vbase2 = 3 * NV + bh * 160;         // gz alongD
    ch = dc;
    const int d0 = dc * RPC + g * 2;

#pragma unroll
    for (int it = 0; it < 2; ++it) {
      const float* rf = fp + (size_t)(d0 + it) * SLICE;
      const float* rt = tp + (size_t)(d0 + it) * SLICE;
      const float4 F0 = *(const float4*)(rf + w);
      const float4 T0 = *(const float4*)(rt + w);
      const float4 FH = *(const float4*)(rf + hstep + w);
      const float4 TH = *(const float4*)(rt + hstep + w);
      const float fz = rf[wn], tz = rt[wn];
#pragma unroll
      for (int j = 0; j < 4; ++j) {
        const float f0 = ELEM(F0, j), t0 = ELEM(T0, j);
        const float gyf = ELEM(FH, j) - f0, gyt = ELEM(TH, j) - t0;
        const float fnx = (j < 3) ? ELEM(F0, j + 1) : fz;
        const float tnx = (j < 3) ? ELEM(T0, j + 1) : tz;
        const float gzf = fnx - f0, gzt = tnx - t0;
        acc[j * 6 + 0] += gyf * gyt; acc[j * 6 + 1] += gyf * gyf; acc[j * 6 + 2] += gyt * gyt;
        acc[j * 6 + 3] += gzf * gzt; acc[j * 6 + 4] += gzf * gzf; acc[j * 6 + 5] += gzt * gzt;
      }
    }
    __syncthreads();                    // zeroed sd2 visible before atomics
  }

  // ---------------- column accumulate (both roles) ----------------
  {
    float* s2 = &sd2[l * 25];
#pragma unroll
    for (int c = 0; c < 24; ++c) atomicAdd(&s2[c], acc[c]);
  }
  __syncthreads();

  if (roleA && tid == 0) {
    float s = 0.0f;
#pragma unroll
    for (int i = 0; i < RPC; ++i) s += cpad[i];
    atomicAdd(out, s * SCALE);
  }
  if (tid < 160) {
    const int ll = tid >> 2, j = tid & 3;           // w-position wi = tid
    const size_t o1 = ((size_t)ch * NVTOT + (vbase1 + tid)) * 3;
    const size_t o2 = ((size_t)ch * NVTOT + (vbase2 + tid)) * 3;
    const float* s2 = &sd2[ll * 25 + j * 6];
    P[o1 + 0] = s2[0]; P[o1 + 1] = s2[1]; P[o1 + 2] = s2[2];
    P[o2 + 0] = s2[3]; P[o2 + 1] = s2[4]; P[o2 + 2] = s2[5];
  }
}

// ---------------------------------------------------------------------------
// Combine chunk partials -> cosines -> loss.
// ---------------------------------------------------------------------------
__global__ __launch_bounds__(256) void finalize_kernel(const float* __restrict__ P,
                                                       float* __restrict__ out) {
  const int v = blockIdx.x * 256 + threadIdx.x;
  float c = 0.0f;
  if (v < NVTOT) {
    float dot = 0.0f, ff = 0.0f, tt = 0.0f;
#pragma unroll
    for (int ch = 0; ch < NC; ++ch) {
      const size_t o = ((size_t)ch * NVTOT + v) * 3;
      dot += P[o]; ff += P[o + 1]; tt += P[o + 2];
    }
    c = dot / (fmaxf(sqrtf(ff), EPS) * fmaxf(sqrtf(tt), EPS));
  }
#pragma unroll
  for (int m = 32; m >= 1; m >>= 1) c += __shfl_xor(c, m);
  __shared__ float part[4];
  if ((threadIdx.x & 63) == 0) part[threadIdx.x >> 6] = c;
  __syncthreads();
  if (threadIdx.x == 0) atomicAdd(out, (part[0] + part[1] + part[2] + part[3]) * SCALE);
}

extern "C" void kernel_launch(void* const* d_in, const int* in_sizes, int n_in,
                              void* d_out, int out_size, void* d_ws, size_t ws_size,
                              hipStream_t stream) {
  const float* fk = (const float*)d_in[0];
  const float* tr = (const float*)d_in[1];
  float* out = (float*)d_out;
  float* P = (float*)d_ws;   // NC*NVTOT*3 floats = 24.6 MB

  hipLaunchKernelGGL(zero_kernel, dim3(1), dim3(64), 0, stream, out);
  hipLaunchKernelGGL(mainAB, dim3(2 * NB * DD * NC), dim3(NTHR), 0, stream, fk, tr, P, out);
  hipLaunchKernelGGL(finalize_kernel, dim3((NVTOT + 255) / 256), dim3(256), 0, stream, P, out);
}

// Round 7
// 149.475 us; speedup vs baseline: 2.4819x; 2.4819x over previous
//
#include <hip/hip_runtime.h>
#include <math.h>

#define DD 160
#define HH 160
#define WW 160
#define NB 2
#define SLICE (HH * WW)        // 25600
#define NV 51200               // NB*160*160 vectors per reduction type
#define NVTOT (4 * NV)         // gxH, gzH, gyD, gzD
#define NC 10                  // chunks per reduced axis
#define RPC 16                 // rows (slices) per chunk
#define NTHR 320               // 8 groups x 40 float4-lanes

static constexpr float EPS = 1e-12f;
static constexpr float SCALE = -1.0f / 960.0f;  // -(six cos sums)/(160*2*3)

#define ELEM(v, j) ((j) == 0 ? (v).x : ((j) == 1 ? (v).y : ((j) == 2 ? (v).z : (v).w)))

__global__ void zero_kernel(float* out) {
  if (threadIdx.x == 0) out[0] = 0.0f;
}

// ---------------------------------------------------------------------------
// Fused main pass (R4 structure: no shuffles, no atomics in hot paths).
// Even blocks: role A (h-walk): alongW cosines (gx,gy) via write-once LDS dump
// + alongH partials (gx,gz) in regs, with register reuse of the h+1 self-load
// across 2 consecutive rows per group. Odd blocks: role B (d-walk): alongD
// partials (gy,gz). Column partials are combined by a write-once hierarchical
// LDS tree (no atomics), reusing the same LDS buffer.
// ---------------------------------------------------------------------------
__global__ __launch_bounds__(NTHR) void mainAB(const float* __restrict__ f,
                                               const float* __restrict__ t,
                                               float* __restrict__ P,
                                               float* __restrict__ out) {
  __shared__ float sd[RPC * 40 * 7];    // 4480 f (17.9 KB); reused as dmp[4][40][25]
  __shared__ float red[RPC][6];
  __shared__ float cpad[RPC];
  const int tid = threadIdx.x;
  const int g = tid / 40;               // group 0..7
  const int l = tid % 40;               // float4-lane within row
  const int w = 4 * l;
  const int wn = (w + 4 < WW) ? (w + 4) : (WW - 1);  // clamp -> gz[3]=0 at w=159
  const int blk = blockIdx.x;
  const bool roleA = ((blk & 1) == 0);
  const int id = blk >> 1;

  float acc[24];                        // alongH (A) or alongD (B) partials
#pragma unroll
  for (int c = 0; c < 24; ++c) acc[c] = 0.0f;

  int vbase1, vbase2, ch;

  if (roleA) {
    // ---------------- role A (h-walk, register-reuse chain) ----------------
    const int hc = id % NC;
    const int bd = id / NC;
    const int d = bd % DD;
    const size_t base = (size_t)bd * SLICE;
    const float* fp = f + base;
    const float* tp = t + base;
    const int dstep = (d < DD - 1) ? SLICE : 0;     // clamp -> gx = 0
    vbase1 = bd * 160;                  // gx alongH
    vbase2 = NV + bd * 160;             // gz alongH
    ch = hc;
    const int h0 = hc * RPC + g * 2;
    float4 F0 = *(const float4*)(fp + h0 * WW + w);
    float4 T0 = *(const float4*)(tp + h0 * WW + w);

#pragma unroll
    for (int it = 0; it < 2; ++it) {
      const int h = h0 + it;
      const int hstep = (h < HH - 1) ? WW : 0;      // clamp -> gy = 0
      const float* rf = fp + h * WW;
      const float* rt = tp + h * WW;
      const float4 FD = *(const float4*)(rf + dstep + w);
      const float4 TD = *(const float4*)(rt + dstep + w);
      const float4 F1 = *(const float4*)(rf + hstep + w);   // row h+1 self
      const float4 T1 = *(const float4*)(rt + hstep + w);
      const float fz = rf[wn], tz = rt[wn];
      float xd = 0, xf = 0, xt = 0, yd = 0, yf = 0, yt = 0;
#pragma unroll
      for (int j = 0; j < 4; ++j) {
        const float f0 = ELEM(F0, j), t0 = ELEM(T0, j);
        const float gxf = ELEM(FD, j) - f0, gxt = ELEM(TD, j) - t0;
        const float gyf = ELEM(F1, j) - f0, gyt = ELEM(T1, j) - t0;
        const float fnx = (j < 3) ? ELEM(F0, j + 1) : fz;
        const float tnx = (j < 3) ? ELEM(T0, j + 1) : tz;
        const float gzf = fnx - f0, gzt = tnx - t0;
        xd += gxf * gxt; xf += gxf * gxf; xt += gxt * gxt;
        yd += gyf * gyt; yf += gyf * gyf; yt += gyt * gyt;
        acc[j * 6 + 0] += gxf * gxt; acc[j * 6 + 1] += gxf * gxf; acc[j * 6 + 2] += gxt * gxt;
        acc[j * 6 + 3] += gzf * gzt; acc[j * 6 + 4] += gzf * gzf; acc[j * 6 + 5] += gzt * gzt;
      }
      F0 = F1; T0 = T1;                 // register reuse: next row's self
      float* s = &sd[((g * 2 + it) * 40 + l) * 7];  // each slot written once
      s[0] = xd; s[1] = xf; s[2] = xt; s[3] = yd; s[4] = yf; s[5] = yt;
    }
    __syncthreads();
    // alongW reduce over 40 lanes: 96 tasks (16 rows x 6 sums)
    if (tid < RPC * 6) {
      const int row = tid / 6, c = tid % 6;
      float s = 0.0f;
#pragma unroll 8
      for (int ll = 0; ll < 40; ++ll) s += sd[(row * 40 + ll) * 7 + c];
      red[row][c] = s;
    }
    __syncthreads();                    // sd now free for reuse as dmp
    if (tid < RPC) {
      const float cx = red[tid][0] / (fmaxf(sqrtf(red[tid][1]), EPS) * fmaxf(sqrtf(red[tid][2]), EPS));
      const float cy = red[tid][3] / (fmaxf(sqrtf(red[tid][4]), EPS) * fmaxf(sqrtf(red[tid][5]), EPS));
      cpad[tid] = cx + cy;
    }
  } else {
    // ---------------- role B (d-walk) ----------------
    const int dc = id % NC;
    const int bh = id / NC;
    const int b = bh / HH;
    const int h = bh % HH;
    const float* fp = f + (size_t)b * DD * SLICE + (size_t)h * WW;
    const float* tp = t + (size_t)b * DD * SLICE + (size_t)h * WW;
    const int hstep = (h < HH - 1) ? WW : 0;        // clamp -> gy = 0
    vbase1 = 2 * NV + bh * 160;         // gy alongD
    vbase2 = 3 * NV + bh * 160;         // gz alongD
    ch = dc;
    const int d0 = dc * RPC + g * 2;

#pragma unroll
    for (int it = 0; it < 2; ++it) {
      const float* rf = fp + (size_t)(d0 + it) * SLICE;
      const float* rt = tp + (size_t)(d0 + it) * SLICE;
      const float4 F0 = *(const float4*)(rf + w);
      const float4 T0 = *(const float4*)(rt + w);
      const float4 FH = *(const float4*)(rf + hstep + w);
      const float4 TH = *(const float4*)(rt + hstep + w);
      const float fz = rf[wn], tz = rt[wn];
#pragma unroll
      for (int j = 0; j < 4; ++j) {
        const float f0 = ELEM(F0, j), t0 = ELEM(T0, j);
        const float gyf = ELEM(FH, j) - f0, gyt = ELEM(TH, j) - t0;
        const float fnx = (j < 3) ? ELEM(F0, j + 1) : fz;
        const float tnx = (j < 3) ? ELEM(T0, j + 1) : tz;
        const float gzf = fnx - f0, gzt = tnx - t0;
        acc[j * 6 + 0] += gyf * gyt; acc[j * 6 + 1] += gyf * gyf; acc[j * 6 + 2] += gyt * gyt;
        acc[j * 6 + 3] += gzf * gzt; acc[j * 6 + 4] += gzf * gzf; acc[j * 6 + 5] += gzt * gzt;
      }
    }
  }

  // ------- column combine: write-once hierarchical tree (no atomics) -------
  // dmp[gg][l][c] := sd[(gg*40+l)*25 + c], gg in 0..3 (4000 floats <= 4480)
  if (g >= 4) {
    float* s2 = &sd[(((g - 4) * 40 + l)) * 25];
#pragma unroll
    for (int c = 0; c < 24; ++c) s2[c] = acc[c];
  }
  __syncthreads();
  if (g < 4) {
    float* s2 = &sd[((g * 40 + l)) * 25];
#pragma unroll
    for (int c = 0; c < 24; ++c) s2[c] += acc[c];
  }
  __syncthreads();
  if (g < 2) {
    float* s2 = &sd[((g * 40 + l)) * 25];
    const float* s3 = &sd[(((g + 2) * 40 + l)) * 25];
#pragma unroll
    for (int c = 0; c < 24; ++c) s2[c] += s3[c];
  }
  __syncthreads();

  if (roleA && tid == 0) {
    float s = 0.0f;
#pragma unroll
    for (int i = 0; i < RPC; ++i) s += cpad[i];
    atomicAdd(out, s * SCALE);
  }
  if (tid < 160) {
    const int ll = tid >> 2, j = tid & 3;           // w-position wi = tid
    const size_t o1 = ((size_t)ch * NVTOT + (vbase1 + tid)) * 3;
    const size_t o2 = ((size_t)ch * NVTOT + (vbase2 + tid)) * 3;
    const float* a0 = &sd[(0 * 40 + ll) * 25 + j * 6];
    const float* a1 = &sd[(1 * 40 + ll) * 25 + j * 6];
    P[o1 + 0] = a0[0] + a1[0]; P[o1 + 1] = a0[1] + a1[1]; P[o1 + 2] = a0[2] + a1[2];
    P[o2 + 0] = a0[3] + a1[3]; P[o2 + 1] = a0[4] + a1[4]; P[o2 + 2] = a0[5] + a1[5];
  }
}

// ---------------------------------------------------------------------------
// Combine chunk partials -> cosines -> loss.
// ---------------------------------------------------------------------------
__global__ __launch_bounds__(256) void finalize_kernel(const float* __restrict__ P,
                                                       float* __restrict__ out) {
  const int v = blockIdx.x * 256 + threadIdx.x;
  float c = 0.0f;
  if (v < NVTOT) {
    float dot = 0.0f, ff = 0.0f, tt = 0.0f;
#pragma unroll
    for (int ch = 0; ch < NC; ++ch) {
      const size_t o = ((size_t)ch * NVTOT + v) * 3;
      dot += P[o]; ff += P[o + 1]; tt += P[o + 2];
    }
    c = dot / (fmaxf(sqrtf(ff), EPS) * fmaxf(sqrtf(tt), EPS));
  }
#pragma unroll
  for (int m = 32; m >= 1; m >>= 1) c += __shfl_xor(c, m);
  __shared__ float part[4];
  if ((threadIdx.x & 63) == 0) part[threadIdx.x >> 6] = c;
  __syncthreads();
  if (threadIdx.x == 0) atomicAdd(out, (part[0] + part[1] + part[2] + part[3]) * SCALE);
}

extern "C" void kernel_launch(void* const* d_in, const int* in_sizes, int n_in,
                              void* d_out, int out_size, void* d_ws, size_t ws_size,
                              hipStream_t stream) {
  const float* fk = (const float*)d_in[0];
  const float* tr = (const float*)d_in[1];
  float* out = (float*)d_out;
  float* P = (float*)d_ws;   // NC*NVTOT*3 floats = 24.6 MB

  hipLaunchKernelGGL(zero_kernel, dim3(1), dim3(64), 0, stream, out);
  hipLaunchKernelGGL(mainAB, dim3(2 * NB * DD * NC), dim3(NTHR), 0, stream, fk, tr, P, out);
  hipLaunchKernelGGL(finalize_kernel, dim3((NVTOT + 255) / 256), dim3(256), 0, stream, P, out);
}